// Round 6
// baseline (221.983 us; speedup 1.0000x reference)
//
#include <hip/hip_runtime.h>

#define NPTS 65536
#define NB 32
#define H 256

typedef __attribute__((ext_vector_type(8))) short bhalf8;   // 8 bf16 = 4 VGPRs
typedef __attribute__((ext_vector_type(4))) float f32x4;

union BHU { bhalf8 h; uint u[4]; };

__device__ __forceinline__ float bf2f(ushort u) {
  union { uint x; float f; } c; c.x = ((uint)u) << 16; return c.f;
}
__device__ __forceinline__ ushort f2bf(float f) {            // RNE
  uint x = __float_as_uint(f);
  uint r = x + 0x7FFFu + ((x >> 16) & 1u);
  return (ushort)(r >> 16);
}
__device__ __forceinline__ uint packrne(float a, float b) {  // two bf16 in a dword
  return (uint)f2bf(a) | ((uint)f2bf(b) << 16);
}
__device__ __forceinline__ float fast_tanh(float z) {
  float e = __expf(2.0f * z);
  return 1.0f - 2.0f / (e + 1.0f);
}

// dtype detect from W1 bit pattern (wave-uniform)
__device__ __forceinline__ bool detect_bf16(const void* W1) {
  const uint4* p = (const uint4*)W1;
  int cnt = 0;
#pragma unroll
  for (int i = 0; i < 8; i++) {
    uint4 v = p[i];
    uint d[4] = {v.x, v.y, v.z, v.w};
#pragma unroll
    for (int k = 0; k < 4; k++) {
      int e = (d[k] >> 7) & 0xFF;                 // exponent of low halfword
      cnt += (e >= 0x70 && e <= 0x7E) ? 1 : 0;
    }
  }
  return cnt >= 16;
}

template<bool B16> __device__ __forceinline__ float LD(const void* p, int i) {
  if constexpr (B16) return bf2f(((const ushort*)p)[i]);
  else               return ((const float*)p)[i];
}
template<bool B16> __device__ __forceinline__ void ST(void* p, int i, float v) {
  if constexpr (B16) ((ushort*)p)[i] = f2bf(v);
  else               ((float*)p)[i] = v;
}

// Pre-swizzle W1 [256][256], W2 [256][32] into MFMA B-frag order (bf16):
// frag(ct,kk): lane l=q*16+r holds B[kk*32+q*8+j][ct*16+r], j=0..7.
__global__ void swz_kernel(const void* W1, const void* W2,
                           ushort* __restrict__ W1s, ushort* __restrict__ W2s) {
  int gid = blockIdx.x * 256 + threadIdx.x;
  bool b16 = detect_bf16(W1);
  if (gid < 65536) {
    int r = gid & 15, q = (gid >> 4) & 3, j = (gid >> 6) & 7;
    int kk = (gid >> 9) & 7, ct = gid >> 12;
    int src = (kk * 32 + q * 8 + j) * H + ct * 16 + r;
    int dst = ((ct * 8 + kk) * 64 + q * 16 + r) * 8 + j;
    float v = b16 ? bf2f(((const ushort*)W1)[src]) : ((const float*)W1)[src];
    W1s[dst] = f2bf(v);
  } else {
    int g2 = gid - 65536;
    int r = g2 & 15, q = (g2 >> 4) & 3, j = (g2 >> 6) & 7;
    int kk = (g2 >> 9) & 7, ct = (g2 >> 12) & 1;
    int src = (kk * 32 + q * 8 + j) * NB + ct * 16 + r;
    int dst = ((ct * 8 + kk) * 64 + q * 16 + r) * 8 + j;
    float v = b16 ? bf2f(((const ushort*)W2)[src]) : ((const float*)W2)[src];
    W2s[dst] = f2bf(v);
  }
}

#define PPITCH 40    // bf16 cols: 80B rows, b128-aligned; 2-way banks on b128 reads

struct Smem {
  alignas(16) ushort pairw[4][48 * PPITCH];  // 15360 B wave-private h1 chunk (bf16)
                                             //   rows 0..31 reused for sin/cos later
  alignas(16) ushort W2l[16 * 64 * 8];       // 16384 B W2 B-frags
  alignas(16) ushort lamTf[2 * 64 * 8];      //  2048 B lambda^T B-frags
  alignas(16) float  w0c[H], b0c[H], b1c[H]; //  3072 B
  alignas(16) float  b2c[NB], lamMc[NB], lamDc[NB]; // 384 B
};                                           // 37248 B -> 4 blocks/CU

template<bool B16>
__device__ void pinn_body(Smem& sm,
                          const void* timeP, const void* powerP,
                          const void* W0, const void* b0,
                          const void* b1, const void* b2,
                          const void* lam_m, const void* lam_d,
                          const void* lam_b, const void* bwi,
                          const ushort* __restrict__ W1s, void* outP) {
  const int tid = threadIdx.x;
  const int wave = tid >> 6, lane = tid & 63;
  const int q = lane >> 4, r = lane & 15;

  // ================= preamble (one barrier) =================
#pragma unroll
  for (int i = 0; i < 4; i++) {
    int c = tid + i * 256;
    *(bhalf8*)(sm.W2l + c * 8) = *(const bhalf8*)(((const ushort*)W1s) + H * H + c * 8);
  }
  if (tid < 128) {   // lambda^T B-frags: lane holds lam_b[ct*16+r][q*8+j]
    int ct = tid >> 6, l2 = tid & 63, qq = l2 >> 4, rr = l2 & 15;
    BHU t;
#pragma unroll
    for (int j = 0; j < 8; j += 2)
      t.u[j >> 1] = packrne(LD<B16>(lam_b, (ct * 16 + rr) * NB + qq * 8 + j),
                            LD<B16>(lam_b, (ct * 16 + rr) * NB + qq * 8 + j + 1));
    *(bhalf8*)(sm.lamTf + tid * 8) = t.h;
  }
  if (tid < H) {
    sm.w0c[tid] = LD<B16>(W0, tid);
    sm.b0c[tid] = LD<B16>(b0, tid);
    sm.b1c[tid] = LD<B16>(b1, tid);
  }
  if (tid < NB) {
    sm.b2c[tid]   = LD<B16>(b2, tid);
    sm.lamMc[tid] = LD<B16>(lam_m, tid) * LD<B16>(bwi, tid);
    sm.lamDc[tid] = LD<B16>(lam_d, tid);
  }
  __syncthreads();

  // ================= wave-autonomous tile =================
  const int s0 = (blockIdx.x * 4 + wave) * 16;
  ushort* pw = &sm.pairw[wave][0];

  float t = LD<B16>(timeP, s0 + r);
  float x = t * 0.1f - 1.0f;               // 2t/TMAX - 1, TMAX = 20

  // ---- A-frags in registers: lane holds Ach[r][kk*32+q*8+j] ----
  bhalf8 a0f[8], a1f[8], a2f[8];
#pragma unroll
  for (int kk = 0; kk < 8; kk++) {
    int k0 = kk * 32 + q * 8;
    BHU t0, t1, t2;
    float vv[8], d1v[8], d2v[8];
#pragma unroll
    for (int j = 0; j < 8; j++) {
      float w0v = sm.w0c[k0 + j];
      float pre = x * w0v + sm.b0c[k0 + j];
      float v = fast_tanh(pre);
      float cc = w0v * 0.1f;
      float s2 = 1.0f - v * v;
      vv[j] = v; d1v[j] = s2 * cc; d2v[j] = -2.0f * v * d1v[j] * cc;
    }
#pragma unroll
    for (int j = 0; j < 8; j += 2) {
      t0.u[j >> 1] = packrne(vv[j], vv[j + 1]);
      t1.u[j >> 1] = packrne(d1v[j], d1v[j + 1]);
      t2.u[j >> 1] = packrne(d2v[j], d2v[j + 1]);
    }
    a0f[kk] = t0.h; a1f[kk] = t1.h; a2f[kk] = t2.h;
  }

  // ---- fused GEMM1 -> tanh chain -> GEMM2, 16 col-tiles ----
  f32x4 acc2[3][2];
#pragma unroll
  for (int ch = 0; ch < 3; ch++)
#pragma unroll
    for (int c2 = 0; c2 < 2; c2++) { f32x4 z = {0.f,0.f,0.f,0.f}; acc2[ch][c2] = z; }

#pragma unroll 1
  for (int ct = 0; ct < 16; ct++) {
    // issue B-frag loads first...
    bhalf8 bf[8];
#pragma unroll
    for (int kk = 0; kk < 8; kk++)
      bf[kk] = *(const bhalf8*)(W1s + ((ct * 8 + kk) * 64 + lane) * 8);

    // ...then consume previous completed pair (independent work covers L2 latency)
    if (ct >= 2 && (ct & 1) == 0) {
      int p = (ct >> 1) - 1;
#pragma unroll
      for (int ch = 0; ch < 3; ch++) {
        bhalf8 hf = *(const bhalf8*)(pw + (ch * 16 + r) * PPITCH + q * 8);
#pragma unroll
        for (int c2i = 0; c2i < 2; c2i++) {
          bhalf8 w2f = *(const bhalf8*)(sm.W2l + ((c2i * 8 + p) * 64 + lane) * 8);
          acc2[ch][c2i] = __builtin_amdgcn_mfma_f32_16x16x32_bf16(hf, w2f, acc2[ch][c2i], 0, 0, 0);
        }
      }
    }

    f32x4 c0 = {0.f,0.f,0.f,0.f}, c1 = c0, c2 = c0;
#pragma unroll
    for (int kk = 0; kk < 8; kk++) {
      c0 = __builtin_amdgcn_mfma_f32_16x16x32_bf16(a0f[kk], bf[kk], c0, 0, 0, 0);
      c1 = __builtin_amdgcn_mfma_f32_16x16x32_bf16(a1f[kk], bf[kk], c1, 0, 0, 0);
      c2 = __builtin_amdgcn_mfma_f32_16x16x32_bf16(a2f[kk], bf[kk], c2, 0, 0, 0);
    }
    // tanh chain on C-layout (col=r, row=q*4+i) -> bf16 pair buffer
    float b1v = sm.b1c[ct * 16 + r];
    int lc = (ct & 1) * 16 + r;
#pragma unroll
    for (int i = 0; i < 4; i++) {
      float hv  = fast_tanh(c0[i] + b1v);
      float s2  = 1.0f - hv * hv;
      float hd  = s2 * c1[i];
      float hdd = s2 * c2[i] - 2.0f * hv * hd * c1[i];
      int row = q * 4 + i;
      pw[row * PPITCH + lc]        = f2bf(hv);
      pw[(16 + row) * PPITCH + lc] = f2bf(hd);
      pw[(32 + row) * PPITCH + lc] = f2bf(hdd);
    }
  }
  // final pair p=7
  {
#pragma unroll
    for (int ch = 0; ch < 3; ch++) {
      bhalf8 hf = *(const bhalf8*)(pw + (ch * 16 + r) * PPITCH + q * 8);
#pragma unroll
      for (int c2i = 0; c2i < 2; c2i++) {
        bhalf8 w2f = *(const bhalf8*)(sm.W2l + ((c2i * 8 + 7) * 64 + lane) * 8);
        acc2[ch][c2i] = __builtin_amdgcn_mfma_f32_16x16x32_bf16(hf, w2f, acc2[ch][c2i], 0, 0, 0);
      }
    }
  }

  // ---- epilogue: angles, sin/cos, coupling via MFMA, physics ----
  float dv[2][4], dt[2][4], dtt[2][4], sn[2][4], cs[2][4], Pv[2][4];
#pragma unroll
  for (int c2 = 0; c2 < 2; c2++) {
    int b = c2 * 16 + r;
    float b2v = sm.b2c[b];
#pragma unroll
    for (int i = 0; i < 4; i++) {
      int n = s0 + q * 4 + i;
      Pv[c2][i] = LD<B16>(powerP, n * NB + b);
      dv[c2][i]  = acc2[0][c2][i] + b2v;
      dt[c2][i]  = acc2[1][c2][i];
      dtt[c2][i] = acc2[2][c2][i];
      sn[c2][i] = __sinf(dv[c2][i]);
      cs[c2][i] = __cosf(dv[c2][i]);
      // reuse pair rows: sin -> rows 0..15, cos -> rows 16..31 (after last pair read)
      pw[(q * 4 + i) * PPITCH + b]        = f2bf(sn[c2][i]);
      pw[(16 + q * 4 + i) * PPITCH + b]   = f2bf(cs[c2][i]);
      ST<B16>(outP, n * NB + b, dv[c2][i]);
      ST<B16>(outP, NPTS * NB + n * NB + b, dt[c2][i]);
    }
  }
  // coupling: C = cos @ lam^T, S = sin @ lam^T  (16x32 @ 32x32 via 16x16x32 MFMA)
  bhalf8 snA = *(const bhalf8*)(pw + r * PPITCH + q * 8);
  bhalf8 csA = *(const bhalf8*)(pw + (16 + r) * PPITCH + q * 8);
  f32x4 accC[2], accS[2];
#pragma unroll
  for (int c2 = 0; c2 < 2; c2++) {
    bhalf8 lt = *(const bhalf8*)(sm.lamTf + (c2 * 64 + lane) * 8);
    f32x4 z = {0.f,0.f,0.f,0.f};
    accC[c2] = __builtin_amdgcn_mfma_f32_16x16x32_bf16(csA, lt, z, 0, 0, 0);
    accS[c2] = __builtin_amdgcn_mfma_f32_16x16x32_bf16(snA, lt, z, 0, 0, 0);
  }
#pragma unroll
  for (int c2 = 0; c2 < 2; c2++) {
    int b = c2 * 16 + r;
    float lm = sm.lamMc[b], ld = sm.lamDc[b];
#pragma unroll
    for (int i = 0; i < 4; i++) {
      float conn = sn[c2][i] * accC[c2][i] - cs[c2][i] * accS[c2][i];
      float phys = lm * dtt[c2][i] + ld * dt[c2][i] + conn - Pv[c2][i];
      int n = s0 + q * 4 + i;
      ST<B16>(outP, 2 * NPTS * NB + n * NB + b, phys);
    }
  }
}

__global__ __launch_bounds__(256, 4)
void pinn_kernel(const void* timeP, const void* powerP,
                 const void* W0, const void* b0,
                 const void* b1, const void* b2,
                 const void* lam_m, const void* lam_d,
                 const void* lam_b, const void* bwi,
                 const void* W1_for_detect,
                 const ushort* __restrict__ W1s, void* outP) {
  __shared__ Smem sm;
  if (detect_bf16(W1_for_detect))
    pinn_body<true>(sm, timeP, powerP, W0, b0, b1, b2, lam_m, lam_d, lam_b, bwi,
                    W1s, outP);
  else
    pinn_body<false>(sm, timeP, powerP, W0, b0, b1, b2, lam_m, lam_d, lam_b, bwi,
                     W1s, outP);
}

extern "C" void kernel_launch(void* const* d_in, const int* in_sizes, int n_in,
                              void* d_out, int out_size, void* d_ws, size_t ws_size,
                              hipStream_t stream) {
  const void* timeP  = d_in[0];
  const void* powerP = d_in[1];
  const void* W0     = d_in[2];
  const void* b0     = d_in[3];
  const void* W1     = d_in[4];
  const void* b1     = d_in[5];
  const void* W2     = d_in[6];
  const void* b2     = d_in[7];
  const void* lam_m  = d_in[8];
  const void* lam_d  = d_in[9];
  const void* lam_b  = d_in[10];
  const void* bwi    = d_in[11];

  ushort* W1s = (ushort*)d_ws;            // W1 frags 128 KB; W2 frags at +65536
  ushort* W2s = W1s + H * H;

  swz_kernel<<<288, 256, 0, stream>>>(W1, W2, W1s, W2s);
  pinn_kernel<<<1024, 256, 0, stream>>>(timeP, powerP, W0, b0, b1, b2,
                                        lam_m, lam_d, lam_b, bwi, W1,
                                        W1s, d_out);
  (void)W2s;
}

// Round 7
// 135.231 us; speedup vs baseline: 1.6415x; 1.6415x over previous
//
#include <hip/hip_runtime.h>

#define NPTS 65536
#define NB 32
#define H 256

typedef __attribute__((ext_vector_type(8))) short bhalf8;   // 8 bf16 = 4 VGPRs
typedef __attribute__((ext_vector_type(4))) float f32x4;

union BHU { bhalf8 h; uint u[4]; };

__device__ __forceinline__ float bf2f(ushort u) {
  union { uint x; float f; } c; c.x = ((uint)u) << 16; return c.f;
}
__device__ __forceinline__ ushort f2bf(float f) {            // RNE
  uint x = __float_as_uint(f);
  uint r = x + 0x7FFFu + ((x >> 16) & 1u);
  return (ushort)(r >> 16);
}
__device__ __forceinline__ uint packrne(float a, float b) {  // two bf16 in a dword
  return (uint)f2bf(a) | ((uint)f2bf(b) << 16);
}
__device__ __forceinline__ float fast_tanh(float z) {
  float e = __expf(2.0f * z);
  return 1.0f - 2.0f / (e + 1.0f);
}

// dtype detect from W1 bit pattern (wave-uniform)
__device__ __forceinline__ bool detect_bf16(const void* W1) {
  const uint4* p = (const uint4*)W1;
  int cnt = 0;
#pragma unroll
  for (int i = 0; i < 8; i++) {
    uint4 v = p[i];
    uint d[4] = {v.x, v.y, v.z, v.w};
#pragma unroll
    for (int k = 0; k < 4; k++) {
      int e = (d[k] >> 7) & 0xFF;                 // exponent of low halfword
      cnt += (e >= 0x70 && e <= 0x7E) ? 1 : 0;
    }
  }
  return cnt >= 16;
}

template<bool B16> __device__ __forceinline__ float LD(const void* p, int i) {
  if constexpr (B16) return bf2f(((const ushort*)p)[i]);
  else               return ((const float*)p)[i];
}
template<bool B16> __device__ __forceinline__ void ST(void* p, int i, float v) {
  if constexpr (B16) ((ushort*)p)[i] = f2bf(v);
  else               ((float*)p)[i] = v;
}

// Pre-swizzle W1 [256][256], W2 [256][32] into MFMA B-frag order (bf16):
// frag(ct,kk): lane l=q*16+r holds B[kk*32+q*8+j][ct*16+r], j=0..7.
__global__ void swz_kernel(const void* W1, const void* W2,
                           ushort* __restrict__ W1s, ushort* __restrict__ W2s) {
  int gid = blockIdx.x * 256 + threadIdx.x;
  bool b16 = detect_bf16(W1);
  if (gid < 65536) {
    int r = gid & 15, q = (gid >> 4) & 3, j = (gid >> 6) & 7;
    int kk = (gid >> 9) & 7, ct = gid >> 12;
    int src = (kk * 32 + q * 8 + j) * H + ct * 16 + r;
    int dst = ((ct * 8 + kk) * 64 + q * 16 + r) * 8 + j;
    float v = b16 ? bf2f(((const ushort*)W1)[src]) : ((const float*)W1)[src];
    W1s[dst] = f2bf(v);
  } else {
    int g2 = gid - 65536;
    int r = g2 & 15, q = (g2 >> 4) & 3, j = (g2 >> 6) & 7;
    int kk = (g2 >> 9) & 7, ct = (g2 >> 12) & 1;
    int src = (kk * 32 + q * 8 + j) * NB + ct * 16 + r;
    int dst = ((ct * 8 + kk) * 64 + q * 16 + r) * 8 + j;
    float v = b16 ? bf2f(((const ushort*)W2)[src]) : ((const float*)W2)[src];
    W2s[dst] = f2bf(v);
  }
}

#define PPITCH 40    // bf16 cols: 80B rows, b128-aligned

struct Smem {
  alignas(16) ushort pairw[4][48 * PPITCH];  // 15360 B wave-private h1 chunk (bf16)
                                             //   rows 0..31 reused for sin/cos later
  alignas(16) ushort W2l[16 * 64 * 8];       // 16384 B W2 B-frags
  alignas(16) ushort lamTf[2 * 64 * 8];      //  2048 B lambda^T B-frags
  alignas(16) float  w0c[H], b0c[H], b1c[H]; //  3072 B
  alignas(16) float  b2c[NB], lamMc[NB], lamDc[NB]; // 384 B
};                                           // 37248 B -> 4 blocks/CU (LDS-wise)

template<bool B16>
__device__ void pinn_body(Smem& sm,
                          const void* timeP, const void* powerP,
                          const void* W0, const void* b0,
                          const void* b1, const void* b2,
                          const void* lam_m, const void* lam_d,
                          const void* lam_b, const void* bwi,
                          const ushort* __restrict__ W1s, void* outP) {
  const int tid = threadIdx.x;
  const int wave = tid >> 6, lane = tid & 63;
  const int q = lane >> 4, r = lane & 15;

  // ================= preamble (one barrier) =================
#pragma unroll
  for (int i = 0; i < 4; i++) {
    int c = tid + i * 256;
    *(bhalf8*)(sm.W2l + c * 8) = *(const bhalf8*)(((const ushort*)W1s) + H * H + c * 8);
  }
  if (tid < 128) {   // lambda^T B-frags: lane holds lam_b[ct*16+r][q*8+j]
    int ct = tid >> 6, l2 = tid & 63, qq = l2 >> 4, rr = l2 & 15;
    BHU t;
#pragma unroll
    for (int j = 0; j < 8; j += 2)
      t.u[j >> 1] = packrne(LD<B16>(lam_b, (ct * 16 + rr) * NB + qq * 8 + j),
                            LD<B16>(lam_b, (ct * 16 + rr) * NB + qq * 8 + j + 1));
    *(bhalf8*)(sm.lamTf + tid * 8) = t.h;
  }
  if (tid < H) {
    sm.w0c[tid] = LD<B16>(W0, tid);
    sm.b0c[tid] = LD<B16>(b0, tid);
    sm.b1c[tid] = LD<B16>(b1, tid);
  }
  if (tid < NB) {
    sm.b2c[tid]   = LD<B16>(b2, tid);
    sm.lamMc[tid] = LD<B16>(lam_m, tid) * LD<B16>(bwi, tid);
    sm.lamDc[tid] = LD<B16>(lam_d, tid);
  }
  __syncthreads();

  // ================= wave-autonomous tile =================
  const int s0 = (blockIdx.x * 4 + wave) * 16;
  ushort* pw = &sm.pairw[wave][0];

  float t = LD<B16>(timeP, s0 + r);
  float x = t * 0.1f - 1.0f;               // 2t/TMAX - 1, TMAX = 20

  // ---- A-frags in registers: lane holds Ach[r][kk*32+q*8+j] ----
  bhalf8 a0f[8], a1f[8], a2f[8];
#pragma unroll
  for (int kk = 0; kk < 8; kk++) {
    int k0 = kk * 32 + q * 8;
    BHU t0, t1, t2;
    float vv[8], d1v[8], d2v[8];
#pragma unroll
    for (int j = 0; j < 8; j++) {
      float w0v = sm.w0c[k0 + j];
      float pre = x * w0v + sm.b0c[k0 + j];
      float v = fast_tanh(pre);
      float cc = w0v * 0.1f;
      float s2 = 1.0f - v * v;
      vv[j] = v; d1v[j] = s2 * cc; d2v[j] = -2.0f * v * d1v[j] * cc;
    }
#pragma unroll
    for (int j = 0; j < 8; j += 2) {
      t0.u[j >> 1] = packrne(vv[j], vv[j + 1]);
      t1.u[j >> 1] = packrne(d1v[j], d1v[j + 1]);
      t2.u[j >> 1] = packrne(d2v[j], d2v[j + 1]);
    }
    a0f[kk] = t0.h; a1f[kk] = t1.h; a2f[kk] = t2.h;
  }

  // ---- fused GEMM1 -> tanh chain -> GEMM2, 16 col-tiles ----
  f32x4 acc2[3][2];
#pragma unroll
  for (int ch = 0; ch < 3; ch++)
#pragma unroll
    for (int c2 = 0; c2 < 2; c2++) { f32x4 z = {0.f,0.f,0.f,0.f}; acc2[ch][c2] = z; }

#pragma unroll 1
  for (int ct = 0; ct < 16; ct++) {
    // issue B-frag loads first...
    bhalf8 bf[8];
#pragma unroll
    for (int kk = 0; kk < 8; kk++)
      bf[kk] = *(const bhalf8*)(W1s + ((ct * 8 + kk) * 64 + lane) * 8);

    // ...then consume previous completed pair (independent work covers L2 latency)
    if (ct >= 2 && (ct & 1) == 0) {
      int p = (ct >> 1) - 1;
#pragma unroll
      for (int ch = 0; ch < 3; ch++) {
        bhalf8 hf = *(const bhalf8*)(pw + (ch * 16 + r) * PPITCH + q * 8);
#pragma unroll
        for (int c2i = 0; c2i < 2; c2i++) {
          bhalf8 w2f = *(const bhalf8*)(sm.W2l + ((c2i * 8 + p) * 64 + lane) * 8);
          acc2[ch][c2i] = __builtin_amdgcn_mfma_f32_16x16x32_bf16(hf, w2f, acc2[ch][c2i], 0, 0, 0);
        }
      }
    }

    f32x4 c0 = {0.f,0.f,0.f,0.f}, c1 = c0, c2 = c0;
#pragma unroll
    for (int kk = 0; kk < 8; kk++) {
      c0 = __builtin_amdgcn_mfma_f32_16x16x32_bf16(a0f[kk], bf[kk], c0, 0, 0, 0);
      c1 = __builtin_amdgcn_mfma_f32_16x16x32_bf16(a1f[kk], bf[kk], c1, 0, 0, 0);
      c2 = __builtin_amdgcn_mfma_f32_16x16x32_bf16(a2f[kk], bf[kk], c2, 0, 0, 0);
    }
    // tanh chain on C-layout (col=r, row=q*4+i) -> bf16 pair buffer
    float b1v = sm.b1c[ct * 16 + r];
    int lc = (ct & 1) * 16 + r;
#pragma unroll
    for (int i = 0; i < 4; i++) {
      float hv  = fast_tanh(c0[i] + b1v);
      float s2  = 1.0f - hv * hv;
      float hd  = s2 * c1[i];
      float hdd = s2 * c2[i] - 2.0f * hv * hd * c1[i];
      int row = q * 4 + i;
      pw[row * PPITCH + lc]        = f2bf(hv);
      pw[(16 + row) * PPITCH + lc] = f2bf(hd);
      pw[(32 + row) * PPITCH + lc] = f2bf(hdd);
    }
  }
  // final pair p=7
  {
#pragma unroll
    for (int ch = 0; ch < 3; ch++) {
      bhalf8 hf = *(const bhalf8*)(pw + (ch * 16 + r) * PPITCH + q * 8);
#pragma unroll
      for (int c2i = 0; c2i < 2; c2i++) {
        bhalf8 w2f = *(const bhalf8*)(sm.W2l + ((c2i * 8 + 7) * 64 + lane) * 8);
        acc2[ch][c2i] = __builtin_amdgcn_mfma_f32_16x16x32_bf16(hf, w2f, acc2[ch][c2i], 0, 0, 0);
      }
    }
  }

  // ---- epilogue: angles, sin/cos, coupling via MFMA, physics ----
  float dv[2][4], dt[2][4], dtt[2][4], sn[2][4], cs[2][4], Pv[2][4];
#pragma unroll
  for (int c2 = 0; c2 < 2; c2++) {
    int b = c2 * 16 + r;
    float b2v = sm.b2c[b];
#pragma unroll
    for (int i = 0; i < 4; i++) {
      int n = s0 + q * 4 + i;
      Pv[c2][i] = LD<B16>(powerP, n * NB + b);
      dv[c2][i]  = acc2[0][c2][i] + b2v;
      dt[c2][i]  = acc2[1][c2][i];
      dtt[c2][i] = acc2[2][c2][i];
      sn[c2][i] = __sinf(dv[c2][i]);
      cs[c2][i] = __cosf(dv[c2][i]);
      // reuse pair rows: sin -> rows 0..15, cos -> rows 16..31 (after last pair read)
      pw[(q * 4 + i) * PPITCH + b]        = f2bf(sn[c2][i]);
      pw[(16 + q * 4 + i) * PPITCH + b]   = f2bf(cs[c2][i]);
      ST<B16>(outP, n * NB + b, dv[c2][i]);
      ST<B16>(outP, NPTS * NB + n * NB + b, dt[c2][i]);
    }
  }
  // coupling: C = cos @ lam^T, S = sin @ lam^T  (16x32 @ 32x32 via 16x16x32 MFMA)
  bhalf8 snA = *(const bhalf8*)(pw + r * PPITCH + q * 8);
  bhalf8 csA = *(const bhalf8*)(pw + (16 + r) * PPITCH + q * 8);
  f32x4 accC[2], accS[2];
#pragma unroll
  for (int c2 = 0; c2 < 2; c2++) {
    bhalf8 lt = *(const bhalf8*)(sm.lamTf + (c2 * 64 + lane) * 8);
    f32x4 z = {0.f,0.f,0.f,0.f};
    accC[c2] = __builtin_amdgcn_mfma_f32_16x16x32_bf16(csA, lt, z, 0, 0, 0);
    accS[c2] = __builtin_amdgcn_mfma_f32_16x16x32_bf16(snA, lt, z, 0, 0, 0);
  }
#pragma unroll
  for (int c2 = 0; c2 < 2; c2++) {
    int b = c2 * 16 + r;
    float lm = sm.lamMc[b], ld = sm.lamDc[b];
#pragma unroll
    for (int i = 0; i < 4; i++) {
      float conn = sn[c2][i] * accC[c2][i] - cs[c2][i] * accS[c2][i];
      float phys = lm * dtt[c2][i] + ld * dt[c2][i] + conn - Pv[c2][i];
      int n = s0 + q * 4 + i;
      ST<B16>(outP, 2 * NPTS * NB + n * NB + b, phys);
    }
  }
}

// __launch_bounds__(256,2): VGPR cap 256 (no spill; r5 frame fit in 128).
// Occupancy comes from LDS (37.3 KB -> 4 blocks/CU) + natural 128-VGPR alloc.
__global__ __launch_bounds__(256, 2)
void pinn_kernel(const void* timeP, const void* powerP,
                 const void* W0, const void* b0,
                 const void* b1, const void* b2,
                 const void* lam_m, const void* lam_d,
                 const void* lam_b, const void* bwi,
                 const void* W1_for_detect,
                 const ushort* __restrict__ W1s, void* outP) {
  __shared__ Smem sm;
  if (detect_bf16(W1_for_detect))
    pinn_body<true>(sm, timeP, powerP, W0, b0, b1, b2, lam_m, lam_d, lam_b, bwi,
                    W1s, outP);
  else
    pinn_body<false>(sm, timeP, powerP, W0, b0, b1, b2, lam_m, lam_d, lam_b, bwi,
                     W1s, outP);
}

extern "C" void kernel_launch(void* const* d_in, const int* in_sizes, int n_in,
                              void* d_out, int out_size, void* d_ws, size_t ws_size,
                              hipStream_t stream) {
  const void* timeP  = d_in[0];
  const void* powerP = d_in[1];
  const void* W0     = d_in[2];
  const void* b0     = d_in[3];
  const void* W1     = d_in[4];
  const void* b1     = d_in[5];
  const void* W2     = d_in[6];
  const void* b2     = d_in[7];
  const void* lam_m  = d_in[8];
  const void* lam_d  = d_in[9];
  const void* lam_b  = d_in[10];
  const void* bwi    = d_in[11];

  ushort* W1s = (ushort*)d_ws;            // W1 frags 128 KB; W2 frags at +65536
  ushort* W2s = W1s + H * H;

  swz_kernel<<<288, 256, 0, stream>>>(W1, W2, W1s, W2s);
  pinn_kernel<<<1024, 256, 0, stream>>>(timeP, powerP, W0, b0, b1, b2,
                                        lam_m, lam_d, lam_b, bwi, W1,
                                        W1s, d_out);
  (void)W2s;
}

// Round 8
// 134.184 us; speedup vs baseline: 1.6543x; 1.0078x over previous
//
#include <hip/hip_runtime.h>

#define NPTS 65536
#define NB 32
#define H 256

typedef __attribute__((ext_vector_type(8))) short bhalf8;   // 8 bf16 = 4 VGPRs
typedef __attribute__((ext_vector_type(4))) float f32x4;

union BHU { bhalf8 h; uint u[4]; };

__device__ __forceinline__ float bf2f(ushort u) {
  union { uint x; float f; } c; c.x = ((uint)u) << 16; return c.f;
}
__device__ __forceinline__ ushort f2bf(float f) {            // RNE (final outputs only)
  uint x = __float_as_uint(f);
  uint r = x + 0x7FFFu + ((x >> 16) & 1u);
  return (ushort)(r >> 16);
}
__device__ __forceinline__ uint packrne(float a, float b) {
  return (uint)f2bf(a) | ((uint)f2bf(b) << 16);
}
// truncating bf16 (1-2 VALU ops) — MFMA inputs / LDS intermediates only
__device__ __forceinline__ ushort trunc1(float f) {
  return (ushort)(__float_as_uint(f) >> 16);
}
__device__ __forceinline__ uint packtr(float a, float b) {   // lshr + and_or = 2 ops
  return (__float_as_uint(a) >> 16) | (__float_as_uint(b) & 0xFFFF0000u);
}
__device__ __forceinline__ float fast_tanh(float z) {
  float e = __expf(2.0f * z);
  return 1.0f - 2.0f / (e + 1.0f);
}

// dtype detect from W1 bit pattern (wave-uniform)
__device__ __forceinline__ bool detect_bf16(const void* W1) {
  const uint4* p = (const uint4*)W1;
  int cnt = 0;
#pragma unroll
  for (int i = 0; i < 8; i++) {
    uint4 v = p[i];
    uint d[4] = {v.x, v.y, v.z, v.w};
#pragma unroll
    for (int k = 0; k < 4; k++) {
      int e = (d[k] >> 7) & 0xFF;                 // exponent of low halfword
      cnt += (e >= 0x70 && e <= 0x7E) ? 1 : 0;
    }
  }
  return cnt >= 16;
}

template<bool B16> __device__ __forceinline__ float LD(const void* p, int i) {
  if constexpr (B16) return bf2f(((const ushort*)p)[i]);
  else               return ((const float*)p)[i];
}
template<bool B16> __device__ __forceinline__ void ST(void* p, int i, float v) {
  if constexpr (B16) ((ushort*)p)[i] = f2bf(v);
  else               ((float*)p)[i] = v;
}

// Pre-swizzle W1 [256][256], W2 [256][32] into MFMA B-frag order (bf16):
// frag(ct,kk): lane l=q*16+r holds B[kk*32+q*8+j][ct*16+r], j=0..7.
__global__ void swz_kernel(const void* W1, const void* W2,
                           ushort* __restrict__ W1s, ushort* __restrict__ W2s) {
  int gid = blockIdx.x * 256 + threadIdx.x;
  bool b16 = detect_bf16(W1);
  if (gid < 65536) {
    int r = gid & 15, q = (gid >> 4) & 3, j = (gid >> 6) & 7;
    int kk = (gid >> 9) & 7, ct = gid >> 12;
    int src = (kk * 32 + q * 8 + j) * H + ct * 16 + r;
    int dst = ((ct * 8 + kk) * 64 + q * 16 + r) * 8 + j;
    float v = b16 ? bf2f(((const ushort*)W1)[src]) : ((const float*)W1)[src];
    W1s[dst] = f2bf(v);
  } else {
    int g2 = gid - 65536;
    int r = g2 & 15, q = (g2 >> 4) & 3, j = (g2 >> 6) & 7;
    int kk = (g2 >> 9) & 7, ct = (g2 >> 12) & 1;
    int src = (kk * 32 + q * 8 + j) * NB + ct * 16 + r;
    int dst = ((ct * 8 + kk) * 64 + q * 16 + r) * 8 + j;
    float v = b16 ? bf2f(((const ushort*)W2)[src]) : ((const float*)W2)[src];
    W2s[dst] = f2bf(v);
  }
}

#define PPITCH 40    // bf16 cols: 80B rows, b128-aligned

struct Smem {
  alignas(16) ushort pairw[4][48 * PPITCH];  // 15360 B wave-private h1 chunk (bf16)
                                             //   rows 0..31 reused for sin/cos later
  alignas(16) ushort W2l[16 * 64 * 8];       // 16384 B W2 B-frags
  alignas(16) ushort lamTf[2 * 64 * 8];      //  2048 B lambda^T B-frags
  alignas(16) float  w0c[H], b0c[H], b1c[H]; //  3072 B
  alignas(16) float  b2c[NB], lamMc[NB], lamDc[NB]; // 384 B
};                                           // 37248 B

template<bool B16>
__device__ void pinn_body(Smem& sm,
                          const void* timeP, const void* powerP,
                          const void* W0, const void* b0,
                          const void* b1, const void* b2,
                          const void* lam_m, const void* lam_d,
                          const void* lam_b, const void* bwi,
                          const ushort* __restrict__ W1s, void* outP) {
  const int tid = threadIdx.x;
  const int wave = tid >> 6, lane = tid & 63;
  const int q = lane >> 4, r = lane & 15;

  // ================= preamble (one barrier) =================
#pragma unroll
  for (int i = 0; i < 4; i++) {
    int c = tid + i * 256;
    *(bhalf8*)(sm.W2l + c * 8) = *(const bhalf8*)(((const ushort*)W1s) + H * H + c * 8);
  }
  if (tid < 128) {   // lambda^T B-frags: lane holds lam_b[ct*16+r][q*8+j]
    int ct = tid >> 6, l2 = tid & 63, qq = l2 >> 4, rr = l2 & 15;
    BHU t;
#pragma unroll
    for (int j = 0; j < 8; j += 2)
      t.u[j >> 1] = packrne(LD<B16>(lam_b, (ct * 16 + rr) * NB + qq * 8 + j),
                            LD<B16>(lam_b, (ct * 16 + rr) * NB + qq * 8 + j + 1));
    *(bhalf8*)(sm.lamTf + tid * 8) = t.h;
  }
  if (tid < H) {
    sm.w0c[tid] = LD<B16>(W0, tid);
    sm.b0c[tid] = LD<B16>(b0, tid);
    sm.b1c[tid] = LD<B16>(b1, tid);
  }
  if (tid < NB) {
    sm.b2c[tid]   = LD<B16>(b2, tid);
    sm.lamMc[tid] = LD<B16>(lam_m, tid) * LD<B16>(bwi, tid);
    sm.lamDc[tid] = LD<B16>(lam_d, tid);
  }
  __syncthreads();

  // ================= wave-autonomous tile =================
  const int s0 = (blockIdx.x * 4 + wave) * 16;
  ushort* pw = &sm.pairw[wave][0];

  float t = LD<B16>(timeP, s0 + r);
  float x = t * 0.1f - 1.0f;               // 2t/TMAX - 1, TMAX = 20

  // ---- A-frags in registers: lane holds Ach[r][kk*32+q*8+j] ----
  bhalf8 a0f[8], a1f[8], a2f[8];
#pragma unroll
  for (int kk = 0; kk < 8; kk++) {
    int k0 = kk * 32 + q * 8;
    float4 wA = *(const float4*)&sm.w0c[k0];
    float4 wB = *(const float4*)&sm.w0c[k0 + 4];
    float4 bA = *(const float4*)&sm.b0c[k0];
    float4 bB = *(const float4*)&sm.b0c[k0 + 4];
    float w0v[8] = {wA.x, wA.y, wA.z, wA.w, wB.x, wB.y, wB.z, wB.w};
    float b0v[8] = {bA.x, bA.y, bA.z, bA.w, bB.x, bB.y, bB.z, bB.w};
    BHU t0, t1, t2;
    float vv[8], d1v[8], d2v[8];
#pragma unroll
    for (int j = 0; j < 8; j++) {
      float v = fast_tanh(x * w0v[j] + b0v[j]);
      float cc = w0v[j] * 0.1f;
      float s2 = 1.0f - v * v;
      vv[j] = v; d1v[j] = s2 * cc; d2v[j] = -2.0f * v * d1v[j] * cc;
    }
#pragma unroll
    for (int j = 0; j < 8; j += 2) {       // truncating pack: 2 ops/pair
      t0.u[j >> 1] = packtr(vv[j], vv[j + 1]);
      t1.u[j >> 1] = packtr(d1v[j], d1v[j + 1]);
      t2.u[j >> 1] = packtr(d2v[j], d2v[j + 1]);
    }
    a0f[kk] = t0.h; a1f[kk] = t1.h; a2f[kk] = t2.h;
  }

  // ---- fused GEMM1 -> tanh chain -> GEMM2, 16 col-tiles ----
  f32x4 acc2[3][2];
#pragma unroll
  for (int ch = 0; ch < 3; ch++)
#pragma unroll
    for (int c2 = 0; c2 < 2; c2++) { f32x4 z = {0.f,0.f,0.f,0.f}; acc2[ch][c2] = z; }

  bhalf8 hf[3];                            // retained pair frags (12 VGPRs, 2-ct life)

#pragma unroll 1
  for (int ct = 0; ct < 16; ct++) {
    // issue B-frag loads first...
    bhalf8 bf[8];
#pragma unroll
    for (int kk = 0; kk < 8; kk++)
      bf[kk] = *(const bhalf8*)(W1s + ((ct * 8 + kk) * 64 + lane) * 8);

    // ...consume previous pair under the load shadow, one c2-half per ct
    if (ct >= 2) {
      int p = (ct >> 1) - 1;
      int c2i = ct & 1;
      if (c2i == 0) {                      // fresh pair: read pw once, keep in regs
#pragma unroll
        for (int ch = 0; ch < 3; ch++)
          hf[ch] = *(const bhalf8*)(pw + (ch * 16 + r) * PPITCH + q * 8);
      }
      bhalf8 w2f = *(const bhalf8*)(sm.W2l + ((c2i * 8 + p) * 64 + lane) * 8);
#pragma unroll
      for (int ch = 0; ch < 3; ch++)
        acc2[ch][c2i] = __builtin_amdgcn_mfma_f32_16x16x32_bf16(hf[ch], w2f, acc2[ch][c2i], 0, 0, 0);
    }

    f32x4 c0 = {0.f,0.f,0.f,0.f}, c1 = c0, c2 = c0;
#pragma unroll
    for (int kk = 0; kk < 8; kk++) {
      c0 = __builtin_amdgcn_mfma_f32_16x16x32_bf16(a0f[kk], bf[kk], c0, 0, 0, 0);
      c1 = __builtin_amdgcn_mfma_f32_16x16x32_bf16(a1f[kk], bf[kk], c1, 0, 0, 0);
      c2 = __builtin_amdgcn_mfma_f32_16x16x32_bf16(a2f[kk], bf[kk], c2, 0, 0, 0);
    }
    // tanh chain on C-layout (col=r, row=q*4+i) -> bf16 pair buffer (trunc writes)
    float b1v = sm.b1c[ct * 16 + r];
    int lc = (ct & 1) * 16 + r;
#pragma unroll
    for (int i = 0; i < 4; i++) {
      float hv  = fast_tanh(c0[i] + b1v);
      float s2  = 1.0f - hv * hv;
      float hd  = s2 * c1[i];
      float hdd = s2 * c2[i] - 2.0f * hv * hd * c1[i];
      int row = q * 4 + i;
      pw[row * PPITCH + lc]        = trunc1(hv);
      pw[(16 + row) * PPITCH + lc] = trunc1(hd);
      pw[(32 + row) * PPITCH + lc] = trunc1(hdd);
    }
  }
  // final pair p=7, both c2 halves
  {
#pragma unroll
    for (int ch = 0; ch < 3; ch++)
      hf[ch] = *(const bhalf8*)(pw + (ch * 16 + r) * PPITCH + q * 8);
#pragma unroll
    for (int c2i = 0; c2i < 2; c2i++) {
      bhalf8 w2f = *(const bhalf8*)(sm.W2l + ((c2i * 8 + 7) * 64 + lane) * 8);
#pragma unroll
      for (int ch = 0; ch < 3; ch++)
        acc2[ch][c2i] = __builtin_amdgcn_mfma_f32_16x16x32_bf16(hf[ch], w2f, acc2[ch][c2i], 0, 0, 0);
    }
  }

  // ---- epilogue: angles, sin/cos, coupling via MFMA, physics ----
  float dv[2][4], dt[2][4], dtt[2][4], sn[2][4], cs[2][4], Pv[2][4];
#pragma unroll
  for (int c2 = 0; c2 < 2; c2++) {
    int b = c2 * 16 + r;
    float b2v = sm.b2c[b];
#pragma unroll
    for (int i = 0; i < 4; i++) {
      int n = s0 + q * 4 + i;
      Pv[c2][i] = LD<B16>(powerP, n * NB + b);
      dv[c2][i]  = acc2[0][c2][i] + b2v;
      dt[c2][i]  = acc2[1][c2][i];
      dtt[c2][i] = acc2[2][c2][i];
      sn[c2][i] = __sinf(dv[c2][i]);
      cs[c2][i] = __cosf(dv[c2][i]);
      // reuse pair rows: sin -> rows 0..15, cos -> rows 16..31 (after last pair read)
      pw[(q * 4 + i) * PPITCH + b]        = trunc1(sn[c2][i]);
      pw[(16 + q * 4 + i) * PPITCH + b]   = trunc1(cs[c2][i]);
      ST<B16>(outP, n * NB + b, dv[c2][i]);
      ST<B16>(outP, NPTS * NB + n * NB + b, dt[c2][i]);
    }
  }
  // coupling: C = cos @ lam^T, S = sin @ lam^T  (16x32 @ 32x32 via 16x16x32 MFMA)
  bhalf8 snA = *(const bhalf8*)(pw + r * PPITCH + q * 8);
  bhalf8 csA = *(const bhalf8*)(pw + (16 + r) * PPITCH + q * 8);
  f32x4 accC[2], accS[2];
#pragma unroll
  for (int c2 = 0; c2 < 2; c2++) {
    bhalf8 lt = *(const bhalf8*)(sm.lamTf + (c2 * 64 + lane) * 8);
    f32x4 z = {0.f,0.f,0.f,0.f};
    accC[c2] = __builtin_amdgcn_mfma_f32_16x16x32_bf16(csA, lt, z, 0, 0, 0);
    accS[c2] = __builtin_amdgcn_mfma_f32_16x16x32_bf16(snA, lt, z, 0, 0, 0);
  }
#pragma unroll
  for (int c2 = 0; c2 < 2; c2++) {
    int b = c2 * 16 + r;
    float lm = sm.lamMc[b], ld = sm.lamDc[b];
#pragma unroll
    for (int i = 0; i < 4; i++) {
      float conn = sn[c2][i] * accC[c2][i] - cs[c2][i] * accS[c2][i];
      float phys = lm * dtt[c2][i] + ld * dt[c2][i] + conn - Pv[c2][i];
      int n = s0 + q * 4 + i;
      ST<B16>(outP, 2 * NPTS * NB + n * NB + b, phys);
    }
  }
}

// (256,2): VGPR cap 256 — no spills (r6's (256,4) spilled to scratch, 400MB fetch).
__global__ __launch_bounds__(256, 2)
void pinn_kernel(const void* timeP, const void* powerP,
                 const void* W0, const void* b0,
                 const void* b1, const void* b2,
                 const void* lam_m, const void* lam_d,
                 const void* lam_b, const void* bwi,
                 const void* W1_for_detect,
                 const ushort* __restrict__ W1s, void* outP) {
  __shared__ Smem sm;
  if (detect_bf16(W1_for_detect))
    pinn_body<true>(sm, timeP, powerP, W0, b0, b1, b2, lam_m, lam_d, lam_b, bwi,
                    W1s, outP);
  else
    pinn_body<false>(sm, timeP, powerP, W0, b0, b1, b2, lam_m, lam_d, lam_b, bwi,
                     W1s, outP);
}

extern "C" void kernel_launch(void* const* d_in, const int* in_sizes, int n_in,
                              void* d_out, int out_size, void* d_ws, size_t ws_size,
                              hipStream_t stream) {
  const void* timeP  = d_in[0];
  const void* powerP = d_in[1];
  const void* W0     = d_in[2];
  const void* b0     = d_in[3];
  const void* W1     = d_in[4];
  const void* b1     = d_in[5];
  const void* W2     = d_in[6];
  const void* b2     = d_in[7];
  const void* lam_m  = d_in[8];
  const void* lam_d  = d_in[9];
  const void* lam_b  = d_in[10];
  const void* bwi    = d_in[11];

  ushort* W1s = (ushort*)d_ws;            // W1 frags 128 KB; W2 frags at +65536
  ushort* W2s = W1s + H * H;

  swz_kernel<<<288, 256, 0, stream>>>(W1, W2, W1s, W2s);
  pinn_kernel<<<1024, 256, 0, stream>>>(timeP, powerP, W0, b0, b1, b2,
                                        lam_m, lam_d, lam_b, bwi, W1,
                                        W1s, d_out);
  (void)W2s;
}

// Round 9
// 129.151 us; speedup vs baseline: 1.7188x; 1.0390x over previous
//
#include <hip/hip_runtime.h>

#define NPTS 65536
#define NB 32
#define H 256

typedef __attribute__((ext_vector_type(8))) short bhalf8;   // 8 bf16 = 4 VGPRs
typedef __attribute__((ext_vector_type(4))) float f32x4;

union BHU { bhalf8 h; uint u[4]; };

__device__ __forceinline__ float bf2f(ushort u) {
  union { uint x; float f; } c; c.x = ((uint)u) << 16; return c.f;
}
__device__ __forceinline__ ushort f2bf(float f) {            // RNE (final outputs only)
  uint x = __float_as_uint(f);
  uint r = x + 0x7FFFu + ((x >> 16) & 1u);
  return (ushort)(r >> 16);
}
__device__ __forceinline__ uint packrne(float a, float b) {
  return (uint)f2bf(a) | ((uint)f2bf(b) << 16);
}
// truncating bf16 (1-2 VALU ops) — MFMA inputs / LDS intermediates only
__device__ __forceinline__ ushort trunc1(float f) {
  return (ushort)(__float_as_uint(f) >> 16);
}
__device__ __forceinline__ uint packtr(float a, float b) {   // lshr + and_or = 2 ops
  return (__float_as_uint(a) >> 16) | (__float_as_uint(b) & 0xFFFF0000u);
}
__device__ __forceinline__ float fast_tanh(float z) {
  float e = __expf(2.0f * z);
  return 1.0f - 2.0f / (e + 1.0f);
}

// dtype detect from W1 bit pattern (wave-uniform)
__device__ __forceinline__ bool detect_bf16(const void* W1) {
  const uint4* p = (const uint4*)W1;
  int cnt = 0;
#pragma unroll
  for (int i = 0; i < 8; i++) {
    uint4 v = p[i];
    uint d[4] = {v.x, v.y, v.z, v.w};
#pragma unroll
    for (int k = 0; k < 4; k++) {
      int e = (d[k] >> 7) & 0xFF;                 // exponent of low halfword
      cnt += (e >= 0x70 && e <= 0x7E) ? 1 : 0;
    }
  }
  return cnt >= 16;
}

template<bool B16> __device__ __forceinline__ float LD(const void* p, int i) {
  if constexpr (B16) return bf2f(((const ushort*)p)[i]);
  else               return ((const float*)p)[i];
}
template<bool B16> __device__ __forceinline__ void ST(void* p, int i, float v) {
  if constexpr (B16) ((ushort*)p)[i] = f2bf(v);
  else               ((float*)p)[i] = v;
}

// Pre-swizzle W1 [256][256], W2 [256][32] into MFMA B-frag order (bf16):
// frag(ct,kk): lane l=q*16+r holds B[kk*32+q*8+j][ct*16+r], j=0..7.
__global__ void swz_kernel(const void* W1, const void* W2,
                           ushort* __restrict__ W1s, ushort* __restrict__ W2s) {
  int gid = blockIdx.x * 256 + threadIdx.x;
  bool b16 = detect_bf16(W1);
  if (gid < 65536) {
    int r = gid & 15, q = (gid >> 4) & 3, j = (gid >> 6) & 7;
    int kk = (gid >> 9) & 7, ct = gid >> 12;
    int src = (kk * 32 + q * 8 + j) * H + ct * 16 + r;
    int dst = ((ct * 8 + kk) * 64 + q * 16 + r) * 8 + j;
    float v = b16 ? bf2f(((const ushort*)W1)[src]) : ((const float*)W1)[src];
    W1s[dst] = f2bf(v);
  } else {
    int g2 = gid - 65536;
    int r = g2 & 15, q = (g2 >> 4) & 3, j = (g2 >> 6) & 7;
    int kk = (g2 >> 9) & 7, ct = (g2 >> 12) & 1;
    int src = (kk * 32 + q * 8 + j) * NB + ct * 16 + r;
    int dst = ((ct * 8 + kk) * 64 + q * 16 + r) * 8 + j;
    float v = b16 ? bf2f(((const ushort*)W2)[src]) : ((const float*)W2)[src];
    W2s[dst] = f2bf(v);
  }
}

#define PPITCH 40    // bf16 cols: 80B rows, b128-aligned

struct Smem {
  alignas(16) ushort pairw[4][48 * PPITCH];  // 15360 B wave-private h1 chunk (bf16)
                                             //   rows 0..31 reused for sin/cos later
  alignas(16) ushort W2l[16 * 64 * 8];       // 16384 B W2 B-frags
  alignas(16) ushort lamTf[2 * 64 * 8];      //  2048 B lambda^T B-frags
  alignas(16) float  w0c[H], b0c[H], b1c[H]; //  3072 B
  alignas(16) float  b2c[NB], lamMc[NB], lamDc[NB]; // 384 B
};                                           // 37248 B

template<bool B16>
__device__ void pinn_body(Smem& sm,
                          const void* timeP, const void* powerP,
                          const void* W0, const void* b0,
                          const void* b1, const void* b2,
                          const void* lam_m, const void* lam_d,
                          const void* lam_b, const void* bwi,
                          const ushort* __restrict__ W1s, void* outP) {
  const int tid = threadIdx.x;
  const int wave = tid >> 6, lane = tid & 63;
  const int q = lane >> 4, r = lane & 15;

  // ================= preamble (one barrier) =================
#pragma unroll
  for (int i = 0; i < 4; i++) {
    int c = tid + i * 256;
    *(bhalf8*)(sm.W2l + c * 8) = *(const bhalf8*)(((const ushort*)W1s) + H * H + c * 8);
  }
  if (tid < 128) {   // lambda^T B-frags: lane holds lam_b[ct*16+r][q*8+j]
    int ct = tid >> 6, l2 = tid & 63, qq = l2 >> 4, rr = l2 & 15;
    BHU t;
#pragma unroll
    for (int j = 0; j < 8; j += 2)
      t.u[j >> 1] = packrne(LD<B16>(lam_b, (ct * 16 + rr) * NB + qq * 8 + j),
                            LD<B16>(lam_b, (ct * 16 + rr) * NB + qq * 8 + j + 1));
    *(bhalf8*)(sm.lamTf + tid * 8) = t.h;
  }
  if (tid < H) {
    sm.w0c[tid] = LD<B16>(W0, tid);
    sm.b0c[tid] = LD<B16>(b0, tid);
    sm.b1c[tid] = LD<B16>(b1, tid);
  }
  if (tid < NB) {
    sm.b2c[tid]   = LD<B16>(b2, tid);
    sm.lamMc[tid] = LD<B16>(lam_m, tid) * LD<B16>(bwi, tid);
    sm.lamDc[tid] = LD<B16>(lam_d, tid);
  }
  __syncthreads();

  // ================= wave-autonomous tile =================
  const int s0 = (blockIdx.x * 4 + wave) * 16;
  ushort* pw = &sm.pairw[wave][0];

  float t = LD<B16>(timeP, s0 + r);
  float x = t * 0.1f - 1.0f;               // 2t/TMAX - 1, TMAX = 20

  // ---- A-frags in registers (AGPR-eligible): lane holds Ach[r][kk*32+q*8+j] ----
  bhalf8 a0f[8], a1f[8], a2f[8];
#pragma unroll
  for (int kk = 0; kk < 8; kk++) {
    int k0 = kk * 32 + q * 8;
    float4 wA = *(const float4*)&sm.w0c[k0];
    float4 wB = *(const float4*)&sm.w0c[k0 + 4];
    float4 bA = *(const float4*)&sm.b0c[k0];
    float4 bB = *(const float4*)&sm.b0c[k0 + 4];
    float w0v[8] = {wA.x, wA.y, wA.z, wA.w, wB.x, wB.y, wB.z, wB.w};
    float b0v[8] = {bA.x, bA.y, bA.z, bA.w, bB.x, bB.y, bB.z, bB.w};
    BHU t0, t1, t2;
    float vv[8], d1v[8], d2v[8];
#pragma unroll
    for (int j = 0; j < 8; j++) {
      float v = fast_tanh(x * w0v[j] + b0v[j]);
      float cc = w0v[j] * 0.1f;
      float s2 = 1.0f - v * v;
      vv[j] = v; d1v[j] = s2 * cc; d2v[j] = -2.0f * v * d1v[j] * cc;
    }
#pragma unroll
    for (int j = 0; j < 8; j += 2) {
      t0.u[j >> 1] = packtr(vv[j], vv[j + 1]);
      t1.u[j >> 1] = packtr(d1v[j], d1v[j + 1]);
      t2.u[j >> 1] = packtr(d2v[j], d2v[j + 1]);
    }
    a0f[kk] = t0.h; a1f[kk] = t1.h; a2f[kk] = t2.h;
  }

  // ---- fused GEMM1 -> tanh chain -> GEMM2; B double-buffered (bfA/bfB) ----
  f32x4 acc2[3][2];
#pragma unroll
  for (int ch = 0; ch < 3; ch++)
#pragma unroll
    for (int c2 = 0; c2 < 2; c2++) { f32x4 z = {0.f,0.f,0.f,0.f}; acc2[ch][c2] = z; }

  bhalf8 bfA[8], bfB[8];
#pragma unroll
  for (int kk = 0; kk < 8; kk++)     // preload ct=0
    bfA[kk] = *(const bhalf8*)(W1s + ((0 * 8 + kk) * 64 + lane) * 8);

#pragma unroll 1
  for (int p = 0; p < 8; p++) {
    const int ct0 = 2 * p, ct1 = 2 * p + 1;

    // issue loads for ct1 into bfB
#pragma unroll
    for (int kk = 0; kk < 8; kk++)
      bfB[kk] = *(const bhalf8*)(W1s + ((ct1 * 8 + kk) * 64 + lane) * 8);

    // consume pair p-1 (LDS-sourced, independent of bfB) under the load shadow
    if (p >= 1) {
      bhalf8 hf0 = *(const bhalf8*)(pw + (0 * 16 + r) * PPITCH + q * 8);
      bhalf8 hf1 = *(const bhalf8*)(pw + (1 * 16 + r) * PPITCH + q * 8);
      bhalf8 hf2 = *(const bhalf8*)(pw + (2 * 16 + r) * PPITCH + q * 8);
#pragma unroll
      for (int c2i = 0; c2i < 2; c2i++) {
        bhalf8 w2f = *(const bhalf8*)(sm.W2l + ((c2i * 8 + (p - 1)) * 64 + lane) * 8);
        acc2[0][c2i] = __builtin_amdgcn_mfma_f32_16x16x32_bf16(hf0, w2f, acc2[0][c2i], 0, 0, 0);
        acc2[1][c2i] = __builtin_amdgcn_mfma_f32_16x16x32_bf16(hf1, w2f, acc2[1][c2i], 0, 0, 0);
        acc2[2][c2i] = __builtin_amdgcn_mfma_f32_16x16x32_bf16(hf2, w2f, acc2[2][c2i], 0, 0, 0);
      }
    }

    // GEMM1 on bfA (ct0) — bfA arrived last iteration
    {
      f32x4 c0 = {0.f,0.f,0.f,0.f}, c1 = c0, c2 = c0;
#pragma unroll
      for (int kk = 0; kk < 8; kk++) {
        c0 = __builtin_amdgcn_mfma_f32_16x16x32_bf16(a0f[kk], bfA[kk], c0, 0, 0, 0);
        c1 = __builtin_amdgcn_mfma_f32_16x16x32_bf16(a1f[kk], bfA[kk], c1, 0, 0, 0);
        c2 = __builtin_amdgcn_mfma_f32_16x16x32_bf16(a2f[kk], bfA[kk], c2, 0, 0, 0);
      }
      float b1v = sm.b1c[ct0 * 16 + r];
#pragma unroll
      for (int i = 0; i < 4; i++) {
        float hv  = fast_tanh(c0[i] + b1v);
        float s2  = 1.0f - hv * hv;
        float hd  = s2 * c1[i];
        float hdd = s2 * c2[i] - 2.0f * hv * hd * c1[i];
        int row = q * 4 + i;
        pw[row * PPITCH + r]        = trunc1(hv);
        pw[(16 + row) * PPITCH + r] = trunc1(hd);
        pw[(32 + row) * PPITCH + r] = trunc1(hdd);
      }
    }

    // issue loads for ct0+2 into bfA (next pair's first buffer)
    if (p < 7) {
#pragma unroll
      for (int kk = 0; kk < 8; kk++)
        bfA[kk] = *(const bhalf8*)(W1s + (((ct0 + 2) * 8 + kk) * 64 + lane) * 8);
    }

    // GEMM1 on bfB (ct1) — latency covered by the 24 MFMAs + chain above
    {
      f32x4 c0 = {0.f,0.f,0.f,0.f}, c1 = c0, c2 = c0;
#pragma unroll
      for (int kk = 0; kk < 8; kk++) {
        c0 = __builtin_amdgcn_mfma_f32_16x16x32_bf16(a0f[kk], bfB[kk], c0, 0, 0, 0);
        c1 = __builtin_amdgcn_mfma_f32_16x16x32_bf16(a1f[kk], bfB[kk], c1, 0, 0, 0);
        c2 = __builtin_amdgcn_mfma_f32_16x16x32_bf16(a2f[kk], bfB[kk], c2, 0, 0, 0);
      }
      float b1v = sm.b1c[ct1 * 16 + r];
      int lc = 16 + r;
#pragma unroll
      for (int i = 0; i < 4; i++) {
        float hv  = fast_tanh(c0[i] + b1v);
        float s2  = 1.0f - hv * hv;
        float hd  = s2 * c1[i];
        float hdd = s2 * c2[i] - 2.0f * hv * hd * c1[i];
        int row = q * 4 + i;
        pw[row * PPITCH + lc]        = trunc1(hv);
        pw[(16 + row) * PPITCH + lc] = trunc1(hd);
        pw[(32 + row) * PPITCH + lc] = trunc1(hdd);
      }
    }
  }
  // final pair p=7
  {
    bhalf8 hf0 = *(const bhalf8*)(pw + (0 * 16 + r) * PPITCH + q * 8);
    bhalf8 hf1 = *(const bhalf8*)(pw + (1 * 16 + r) * PPITCH + q * 8);
    bhalf8 hf2 = *(const bhalf8*)(pw + (2 * 16 + r) * PPITCH + q * 8);
#pragma unroll
    for (int c2i = 0; c2i < 2; c2i++) {
      bhalf8 w2f = *(const bhalf8*)(sm.W2l + ((c2i * 8 + 7) * 64 + lane) * 8);
      acc2[0][c2i] = __builtin_amdgcn_mfma_f32_16x16x32_bf16(hf0, w2f, acc2[0][c2i], 0, 0, 0);
      acc2[1][c2i] = __builtin_amdgcn_mfma_f32_16x16x32_bf16(hf1, w2f, acc2[1][c2i], 0, 0, 0);
      acc2[2][c2i] = __builtin_amdgcn_mfma_f32_16x16x32_bf16(hf2, w2f, acc2[2][c2i], 0, 0, 0);
    }
  }

  // ---- epilogue: angles, sin/cos, coupling via MFMA, physics ----
  float dv[2][4], dt[2][4], dtt[2][4], sn[2][4], cs[2][4], Pv[2][4];
#pragma unroll
  for (int c2 = 0; c2 < 2; c2++) {
    int b = c2 * 16 + r;
    float b2v = sm.b2c[b];
#pragma unroll
    for (int i = 0; i < 4; i++) {
      int n = s0 + q * 4 + i;
      Pv[c2][i] = LD<B16>(powerP, n * NB + b);
      dv[c2][i]  = acc2[0][c2][i] + b2v;
      dt[c2][i]  = acc2[1][c2][i];
      dtt[c2][i] = acc2[2][c2][i];
      __sincosf(dv[c2][i], &sn[c2][i], &cs[c2][i]);
      // reuse pair rows: sin -> rows 0..15, cos -> rows 16..31 (after last pair read)
      pw[(q * 4 + i) * PPITCH + b]        = trunc1(sn[c2][i]);
      pw[(16 + q * 4 + i) * PPITCH + b]   = trunc1(cs[c2][i]);
      ST<B16>(outP, n * NB + b, dv[c2][i]);
      ST<B16>(outP, NPTS * NB + n * NB + b, dt[c2][i]);
    }
  }
  // coupling: C = cos @ lam^T, S = sin @ lam^T  (16x32 @ 32x32 via 16x16x32 MFMA)
  bhalf8 snA = *(const bhalf8*)(pw + r * PPITCH + q * 8);
  bhalf8 csA = *(const bhalf8*)(pw + (16 + r) * PPITCH + q * 8);
  f32x4 accC[2], accS[2];
#pragma unroll
  for (int c2 = 0; c2 < 2; c2++) {
    bhalf8 lt = *(const bhalf8*)(sm.lamTf + (c2 * 64 + lane) * 8);
    f32x4 z = {0.f,0.f,0.f,0.f};
    accC[c2] = __builtin_amdgcn_mfma_f32_16x16x32_bf16(csA, lt, z, 0, 0, 0);
    accS[c2] = __builtin_amdgcn_mfma_f32_16x16x32_bf16(snA, lt, z, 0, 0, 0);
  }
#pragma unroll
  for (int c2 = 0; c2 < 2; c2++) {
    int b = c2 * 16 + r;
    float lm = sm.lamMc[b], ld = sm.lamDc[b];
#pragma unroll
    for (int i = 0; i < 4; i++) {
      float conn = sn[c2][i] * accC[c2][i] - cs[c2][i] * accS[c2][i];
      float phys = lm * dtt[c2][i] + ld * dt[c2][i] + conn - Pv[c2][i];
      int n = s0 + q * 4 + i;
      ST<B16>(outP, 2 * NPTS * NB + n * NB + b, phys);
    }
  }
}

// (256,2): VGPR cap 256 — no spills (r6's (256,4) spilled to scratch, 400MB fetch).
__global__ __launch_bounds__(256, 2)
void pinn_kernel(const void* timeP, const void* powerP,
                 const void* W0, const void* b0,
                 const void* b1, const void* b2,
                 const void* lam_m, const void* lam_d,
                 const void* lam_b, const void* bwi,
                 const void* W1_for_detect,
                 const ushort* __restrict__ W1s, void* outP) {
  __shared__ Smem sm;
  if (detect_bf16(W1_for_detect))
    pinn_body<true>(sm, timeP, powerP, W0, b0, b1, b2, lam_m, lam_d, lam_b, bwi,
                    W1s, outP);
  else
    pinn_body<false>(sm, timeP, powerP, W0, b0, b1, b2, lam_m, lam_d, lam_b, bwi,
                     W1s, outP);
}

extern "C" void kernel_launch(void* const* d_in, const int* in_sizes, int n_in,
                              void* d_out, int out_size, void* d_ws, size_t ws_size,
                              hipStream_t stream) {
  const void* timeP  = d_in[0];
  const void* powerP = d_in[1];
  const void* W0     = d_in[2];
  const void* b0     = d_in[3];
  const void* W1     = d_in[4];
  const void* b1     = d_in[5];
  const void* W2     = d_in[6];
  const void* b2     = d_in[7];
  const void* lam_m  = d_in[8];
  const void* lam_d  = d_in[9];
  const void* lam_b  = d_in[10];
  const void* bwi    = d_in[11];

  ushort* W1s = (ushort*)d_ws;            // W1 frags 128 KB; W2 frags at +65536
  ushort* W2s = W1s + H * H;

  swz_kernel<<<288, 256, 0, stream>>>(W1, W2, W1s, W2s);
  pinn_kernel<<<1024, 256, 0, stream>>>(timeP, powerP, W0, b0, b1, b2,
                                        lam_m, lam_d, lam_b, bwi, W1,
                                        W1s, d_out);
  (void)W2s;
}

// Round 10
// 123.328 us; speedup vs baseline: 1.7999x; 1.0472x over previous
//
#include <hip/hip_runtime.h>

#define NPTS 65536
#define NB 32
#define H 256
#define K2E 2.8853900817779268f   // 2*log2(e): tanh(z)=1-2/(exp2(K2E*z)+1)

typedef __attribute__((ext_vector_type(8))) short bhalf8;   // 8 bf16 = 4 VGPRs
typedef __attribute__((ext_vector_type(4))) float f32x4;

union BHU { bhalf8 h; uint u[4]; };

__device__ __forceinline__ float bf2f(ushort u) {
  union { uint x; float f; } c; c.x = ((uint)u) << 16; return c.f;
}
__device__ __forceinline__ ushort f2bf(float f) {            // RNE (final outputs only)
  uint x = __float_as_uint(f);
  uint r = x + 0x7FFFu + ((x >> 16) & 1u);
  return (ushort)(r >> 16);
}
__device__ __forceinline__ uint packrne(float a, float b) {
  return (uint)f2bf(a) | ((uint)f2bf(b) << 16);
}
// truncating bf16 — MFMA inputs / LDS intermediates only
__device__ __forceinline__ ushort trunc1(float f) {
  return (ushort)(__float_as_uint(f) >> 16);
}
__device__ __forceinline__ uint packtr(float a, float b) {
  return (__float_as_uint(a) >> 16) | (__float_as_uint(b) & 0xFFFF0000u);
}
// tanh with pre-folded 2*log2e arg: v_exp + v_add + v_rcp + v_fma (no div sequence!)
__device__ __forceinline__ float tanh_pf(float z2e) {
  float e = exp2f(z2e);
  float r = __builtin_amdgcn_rcpf(e + 1.0f);
  return fmaf(-2.0f, r, 1.0f);
}

// dtype detect from W1 bit pattern (wave-uniform)
__device__ __forceinline__ bool detect_bf16(const void* W1) {
  const uint4* p = (const uint4*)W1;
  int cnt = 0;
#pragma unroll
  for (int i = 0; i < 8; i++) {
    uint4 v = p[i];
    uint d[4] = {v.x, v.y, v.z, v.w};
#pragma unroll
    for (int k = 0; k < 4; k++) {
      int e = (d[k] >> 7) & 0xFF;                 // exponent of low halfword
      cnt += (e >= 0x70 && e <= 0x7E) ? 1 : 0;
    }
  }
  return cnt >= 16;
}

template<bool B16> __device__ __forceinline__ float LD(const void* p, int i) {
  if constexpr (B16) return bf2f(((const ushort*)p)[i]);
  else               return ((const float*)p)[i];
}
template<bool B16> __device__ __forceinline__ void ST(void* p, int i, float v) {
  if constexpr (B16) ((ushort*)p)[i] = f2bf(v);
  else               ((float*)p)[i] = v;
}

// Pre-swizzle W1 [256][256], W2 [256][32] into MFMA B-frag order (bf16):
// frag(ct,kk): lane l=q*16+r holds B[kk*32+q*8+j][ct*16+r], j=0..7.
__global__ void swz_kernel(const void* W1, const void* W2,
                           ushort* __restrict__ W1s, ushort* __restrict__ W2s) {
  int gid = blockIdx.x * 256 + threadIdx.x;
  bool b16 = detect_bf16(W1);
  if (gid < 65536) {
    int r = gid & 15, q = (gid >> 4) & 3, j = (gid >> 6) & 7;
    int kk = (gid >> 9) & 7, ct = gid >> 12;
    int src = (kk * 32 + q * 8 + j) * H + ct * 16 + r;
    int dst = ((ct * 8 + kk) * 64 + q * 16 + r) * 8 + j;
    float v = b16 ? bf2f(((const ushort*)W1)[src]) : ((const float*)W1)[src];
    W1s[dst] = f2bf(v);
  } else {
    int g2 = gid - 65536;
    int r = g2 & 15, q = (g2 >> 4) & 3, j = (g2 >> 6) & 7;
    int kk = (g2 >> 9) & 7, ct = (g2 >> 12) & 1;
    int src = (kk * 32 + q * 8 + j) * NB + ct * 16 + r;
    int dst = ((ct * 8 + kk) * 64 + q * 16 + r) * 8 + j;
    float v = b16 ? bf2f(((const ushort*)W2)[src]) : ((const float*)W2)[src];
    W2s[dst] = f2bf(v);
  }
}

#define PPITCH 40    // bf16 cols: 80B rows, b128-aligned

struct Smem {
  alignas(16) ushort pairw[4][48 * PPITCH];  // 15360 B wave-private h1 chunk (bf16)
                                             //   rows 0..31 reused for sin/cos later
  alignas(16) ushort W2l[16 * 64 * 8];       // 16384 B W2 B-frags
  alignas(16) ushort lamTf[2 * 64 * 8];      //  2048 B lambda^T B-frags
  alignas(16) float  w0c[H], w0e[H], b0e[H], b1e[H]; // 4096 B (pre-folded K2E copies)
  alignas(16) float  b2c[NB], lamMc[NB], lamDc[NB]; // 384 B
};                                           // 38272 B (<=40KB: 4 blocks/CU LDS-wise)

template<bool B16>
__device__ void pinn_body(Smem& sm,
                          const void* timeP, const void* powerP,
                          const void* W0, const void* b0,
                          const void* b1, const void* b2,
                          const void* lam_m, const void* lam_d,
                          const void* lam_b, const void* bwi,
                          const ushort* __restrict__ W1s, void* outP) {
  const int tid = threadIdx.x;
  const int wave = tid >> 6, lane = tid & 63;
  const int q = lane >> 4, r = lane & 15;

  // ================= preamble (one barrier) =================
#pragma unroll
  for (int i = 0; i < 4; i++) {
    int c = tid + i * 256;
    *(bhalf8*)(sm.W2l + c * 8) = *(const bhalf8*)(((const ushort*)W1s) + H * H + c * 8);
  }
  if (tid < 128) {   // lambda^T B-frags: lane holds lam_b[ct*16+r][q*8+j]
    int ct = tid >> 6, l2 = tid & 63, qq = l2 >> 4, rr = l2 & 15;
    BHU t;
#pragma unroll
    for (int j = 0; j < 8; j += 2)
      t.u[j >> 1] = packrne(LD<B16>(lam_b, (ct * 16 + rr) * NB + qq * 8 + j),
                            LD<B16>(lam_b, (ct * 16 + rr) * NB + qq * 8 + j + 1));
    *(bhalf8*)(sm.lamTf + tid * 8) = t.h;
  }
  if (tid < H) {
    float w0v = LD<B16>(W0, tid);
    sm.w0c[tid] = w0v;
    sm.w0e[tid] = K2E * w0v;
    sm.b0e[tid] = K2E * LD<B16>(b0, tid);
    sm.b1e[tid] = K2E * LD<B16>(b1, tid);
  }
  if (tid < NB) {
    sm.b2c[tid]   = LD<B16>(b2, tid);
    sm.lamMc[tid] = LD<B16>(lam_m, tid) * LD<B16>(bwi, tid);
    sm.lamDc[tid] = LD<B16>(lam_d, tid);
  }
  __syncthreads();

  // ================= wave-autonomous tile =================
  const int s0 = (blockIdx.x * 4 + wave) * 16;
  ushort* pw = &sm.pairw[wave][0];

  float t = LD<B16>(timeP, s0 + r);
  float x = t * 0.1f - 1.0f;               // 2t/TMAX - 1, TMAX = 20

  // ---- A-frags in registers: lane holds Ach[r][kk*32+q*8+j] ----
  bhalf8 a0f[8], a1f[8], a2f[8];
#pragma unroll
  for (int kk = 0; kk < 8; kk++) {
    int k0 = kk * 32 + q * 8;
    float4 wA = *(const float4*)&sm.w0c[k0];
    float4 wB = *(const float4*)&sm.w0c[k0 + 4];
    float4 eA = *(const float4*)&sm.w0e[k0];
    float4 eB = *(const float4*)&sm.w0e[k0 + 4];
    float4 bA = *(const float4*)&sm.b0e[k0];
    float4 bB = *(const float4*)&sm.b0e[k0 + 4];
    float w0v[8] = {wA.x, wA.y, wA.z, wA.w, wB.x, wB.y, wB.z, wB.w};
    float w0ev[8] = {eA.x, eA.y, eA.z, eA.w, eB.x, eB.y, eB.z, eB.w};
    float b0ev[8] = {bA.x, bA.y, bA.z, bA.w, bB.x, bB.y, bB.z, bB.w};
    BHU t0, t1, t2;
    float vv[8], d1v[8], d2v[8];
#pragma unroll
    for (int j = 0; j < 8; j++) {
      float v = tanh_pf(fmaf(x, w0ev[j], b0ev[j]));
      float cc = w0v[j] * 0.1f;
      float s2 = 1.0f - v * v;
      vv[j] = v; d1v[j] = s2 * cc; d2v[j] = -2.0f * v * d1v[j] * cc;
    }
#pragma unroll
    for (int j = 0; j < 8; j += 2) {
      t0.u[j >> 1] = packtr(vv[j], vv[j + 1]);
      t1.u[j >> 1] = packtr(d1v[j], d1v[j + 1]);
      t2.u[j >> 1] = packtr(d2v[j], d2v[j + 1]);
    }
    a0f[kk] = t0.h; a1f[kk] = t1.h; a2f[kk] = t2.h;
  }

  // ---- fused GEMM1 -> tanh chain -> GEMM2; B double-buffered (bfA/bfB) ----
  f32x4 acc2[3][2];
#pragma unroll
  for (int ch = 0; ch < 3; ch++)
#pragma unroll
    for (int c2 = 0; c2 < 2; c2++) { f32x4 z = {0.f,0.f,0.f,0.f}; acc2[ch][c2] = z; }

  bhalf8 bfA[8], bfB[8];
#pragma unroll
  for (int kk = 0; kk < 8; kk++)     // preload ct=0
    bfA[kk] = *(const bhalf8*)(W1s + ((0 * 8 + kk) * 64 + lane) * 8);

#pragma unroll 1
  for (int p = 0; p < 8; p++) {
    const int ct0 = 2 * p, ct1 = 2 * p + 1;

    // issue loads for ct1 into bfB
#pragma unroll
    for (int kk = 0; kk < 8; kk++)
      bfB[kk] = *(const bhalf8*)(W1s + ((ct1 * 8 + kk) * 64 + lane) * 8);

    // GEMM1 on bfA (ct0) — arrived last iteration
    f32x4 c0 = {0.f,0.f,0.f,0.f}, c1 = c0, c2 = c0;
#pragma unroll
    for (int kk = 0; kk < 8; kk++) {
      c0 = __builtin_amdgcn_mfma_f32_16x16x32_bf16(a0f[kk], bfA[kk], c0, 0, 0, 0);
      c1 = __builtin_amdgcn_mfma_f32_16x16x32_bf16(a1f[kk], bfA[kk], c1, 0, 0, 0);
      c2 = __builtin_amdgcn_mfma_f32_16x16x32_bf16(a2f[kk], bfA[kk], c2, 0, 0, 0);
    }

    // consume pair p-1 AFTER GEMM1-bfA: maximizes pw write->read gap AND
    // covers the MFMA-result latency before chain-A reads c0/c1/c2
    if (p >= 1) {
      bhalf8 hf0 = *(const bhalf8*)(pw + (0 * 16 + r) * PPITCH + q * 8);
      bhalf8 hf1 = *(const bhalf8*)(pw + (1 * 16 + r) * PPITCH + q * 8);
      bhalf8 hf2 = *(const bhalf8*)(pw + (2 * 16 + r) * PPITCH + q * 8);
#pragma unroll
      for (int c2i = 0; c2i < 2; c2i++) {
        bhalf8 w2f = *(const bhalf8*)(sm.W2l + ((c2i * 8 + (p - 1)) * 64 + lane) * 8);
        acc2[0][c2i] = __builtin_amdgcn_mfma_f32_16x16x32_bf16(hf0, w2f, acc2[0][c2i], 0, 0, 0);
        acc2[1][c2i] = __builtin_amdgcn_mfma_f32_16x16x32_bf16(hf1, w2f, acc2[1][c2i], 0, 0, 0);
        acc2[2][c2i] = __builtin_amdgcn_mfma_f32_16x16x32_bf16(hf2, w2f, acc2[2][c2i], 0, 0, 0);
      }
    }

    // chain-A (ct0) -> pw cols 0..15
    {
      float b1v = sm.b1e[ct0 * 16 + r];
#pragma unroll
      for (int i = 0; i < 4; i++) {
        float hv  = tanh_pf(fmaf(c0[i], K2E, b1v));
        float s2  = 1.0f - hv * hv;
        float hd  = s2 * c1[i];
        float hdd = s2 * c2[i] - 2.0f * hv * hd * c1[i];
        int row = q * 4 + i;
        pw[row * PPITCH + r]        = trunc1(hv);
        pw[(16 + row) * PPITCH + r] = trunc1(hd);
        pw[(32 + row) * PPITCH + r] = trunc1(hdd);
      }
    }

    // issue loads for ct0+2 into bfA (next pair's first buffer)
    if (p < 7) {
#pragma unroll
      for (int kk = 0; kk < 8; kk++)
        bfA[kk] = *(const bhalf8*)(W1s + (((ct0 + 2) * 8 + kk) * 64 + lane) * 8);
    }

    // GEMM1 on bfB (ct1) — latency covered by all the work above
    {
      f32x4 d0 = {0.f,0.f,0.f,0.f}, d1 = d0, d2 = d0;
#pragma unroll
      for (int kk = 0; kk < 8; kk++) {
        d0 = __builtin_amdgcn_mfma_f32_16x16x32_bf16(a0f[kk], bfB[kk], d0, 0, 0, 0);
        d1 = __builtin_amdgcn_mfma_f32_16x16x32_bf16(a1f[kk], bfB[kk], d1, 0, 0, 0);
        d2 = __builtin_amdgcn_mfma_f32_16x16x32_bf16(a2f[kk], bfB[kk], d2, 0, 0, 0);
      }
      float b1v = sm.b1e[ct1 * 16 + r];
      int lc = 16 + r;
#pragma unroll
      for (int i = 0; i < 4; i++) {
        float hv  = tanh_pf(fmaf(d0[i], K2E, b1v));
        float s2  = 1.0f - hv * hv;
        float hd  = s2 * d1[i];
        float hdd = s2 * d2[i] - 2.0f * hv * hd * d1[i];
        int row = q * 4 + i;
        pw[row * PPITCH + lc]        = trunc1(hv);
        pw[(16 + row) * PPITCH + lc] = trunc1(hd);
        pw[(32 + row) * PPITCH + lc] = trunc1(hdd);
      }
    }
  }
  // final pair p=7
  {
    bhalf8 hf0 = *(const bhalf8*)(pw + (0 * 16 + r) * PPITCH + q * 8);
    bhalf8 hf1 = *(const bhalf8*)(pw + (1 * 16 + r) * PPITCH + q * 8);
    bhalf8 hf2 = *(const bhalf8*)(pw + (2 * 16 + r) * PPITCH + q * 8);
#pragma unroll
    for (int c2i = 0; c2i < 2; c2i++) {
      bhalf8 w2f = *(const bhalf8*)(sm.W2l + ((c2i * 8 + 7) * 64 + lane) * 8);
      acc2[0][c2i] = __builtin_amdgcn_mfma_f32_16x16x32_bf16(hf0, w2f, acc2[0][c2i], 0, 0, 0);
      acc2[1][c2i] = __builtin_amdgcn_mfma_f32_16x16x32_bf16(hf1, w2f, acc2[1][c2i], 0, 0, 0);
      acc2[2][c2i] = __builtin_amdgcn_mfma_f32_16x16x32_bf16(hf2, w2f, acc2[2][c2i], 0, 0, 0);
    }
  }

  // ---- epilogue: angles, sin/cos, coupling via MFMA, physics ----
  float dv[2][4], dt[2][4], dtt[2][4], sn[2][4], cs[2][4], Pv[2][4];
#pragma unroll
  for (int c2 = 0; c2 < 2; c2++) {
    int b = c2 * 16 + r;
    float b2v = sm.b2c[b];
#pragma unroll
    for (int i = 0; i < 4; i++) {
      int n = s0 + q * 4 + i;
      Pv[c2][i] = LD<B16>(powerP, n * NB + b);
      dv[c2][i]  = acc2[0][c2][i] + b2v;
      dt[c2][i]  = acc2[1][c2][i];
      dtt[c2][i] = acc2[2][c2][i];
      __sincosf(dv[c2][i], &sn[c2][i], &cs[c2][i]);
      // reuse pair rows: sin -> rows 0..15, cos -> rows 16..31 (after last pair read)
      pw[(q * 4 + i) * PPITCH + b]        = trunc1(sn[c2][i]);
      pw[(16 + q * 4 + i) * PPITCH + b]   = trunc1(cs[c2][i]);
      ST<B16>(outP, n * NB + b, dv[c2][i]);
      ST<B16>(outP, NPTS * NB + n * NB + b, dt[c2][i]);
    }
  }
  // coupling: C = cos @ lam^T, S = sin @ lam^T  (16x32 @ 32x32 via 16x16x32 MFMA)
  bhalf8 snA = *(const bhalf8*)(pw + r * PPITCH + q * 8);
  bhalf8 csA = *(const bhalf8*)(pw + (16 + r) * PPITCH + q * 8);
  f32x4 accC[2], accS[2];
#pragma unroll
  for (int c2 = 0; c2 < 2; c2++) {
    bhalf8 lt = *(const bhalf8*)(sm.lamTf + (c2 * 64 + lane) * 8);
    f32x4 z = {0.f,0.f,0.f,0.f};
    accC[c2] = __builtin_amdgcn_mfma_f32_16x16x32_bf16(csA, lt, z, 0, 0, 0);
    accS[c2] = __builtin_amdgcn_mfma_f32_16x16x32_bf16(snA, lt, z, 0, 0, 0);
  }
#pragma unroll
  for (int c2 = 0; c2 < 2; c2++) {
    int b = c2 * 16 + r;
    float lm = sm.lamMc[b], ld = sm.lamDc[b];
#pragma unroll
    for (int i = 0; i < 4; i++) {
      float conn = sn[c2][i] * accC[c2][i] - cs[c2][i] * accS[c2][i];
      float phys = lm * dtt[c2][i] + ld * dt[c2][i] + conn - Pv[c2][i];
      int n = s0 + q * 4 + i;
      ST<B16>(outP, 2 * NPTS * NB + n * NB + b, phys);
    }
  }
}

// (256,2): VGPR cap 256 — no spills (r6's (256,4) spilled to scratch, 400MB fetch).
__global__ __launch_bounds__(256, 2)
void pinn_kernel(const void* timeP, const void* powerP,
                 const void* W0, const void* b0,
                 const void* b1, const void* b2,
                 const void* lam_m, const void* lam_d,
                 const void* lam_b, const void* bwi,
                 const void* W1_for_detect,
                 const ushort* __restrict__ W1s, void* outP) {
  __shared__ Smem sm;
  if (detect_bf16(W1_for_detect))
    pinn_body<true>(sm, timeP, powerP, W0, b0, b1, b2, lam_m, lam_d, lam_b, bwi,
                    W1s, outP);
  else
    pinn_body<false>(sm, timeP, powerP, W0, b0, b1, b2, lam_m, lam_d, lam_b, bwi,
                     W1s, outP);
}

extern "C" void kernel_launch(void* const* d_in, const int* in_sizes, int n_in,
                              void* d_out, int out_size, void* d_ws, size_t ws_size,
                              hipStream_t stream) {
  const void* timeP  = d_in[0];
  const void* powerP = d_in[1];
  const void* W0     = d_in[2];
  const void* b0     = d_in[3];
  const void* W1     = d_in[4];
  const void* b1     = d_in[5];
  const void* W2     = d_in[6];
  const void* b2     = d_in[7];
  const void* lam_m  = d_in[8];
  const void* lam_d  = d_in[9];
  const void* lam_b  = d_in[10];
  const void* bwi    = d_in[11];

  ushort* W1s = (ushort*)d_ws;            // W1 frags 128 KB; W2 frags at +65536
  ushort* W2s = W1s + H * H;

  swz_kernel<<<288, 256, 0, stream>>>(W1, W2, W1s, W2s);
  pinn_kernel<<<1024, 256, 0, stream>>>(timeP, powerP, W0, b0, b1, b2,
                                        lam_m, lam_d, lam_b, bwi, W1,
                                        W1s, d_out);
  (void)W2s;
}